// Round 11
// baseline (246.490 us; speedup 1.0000x reference)
//
#include <hip/hip_runtime.h>
#include <math.h>

#define D 128
#define KNN 8
#define NSPLIT 8
#define NT 4                       // column tiles staged per batch (one per wave)
#define BIGF 3.0e38f
#define C_L2E2 2.0813689810056077f // (log2 e)^2
#define LN2 0.6931471805599453f

typedef __bf16 bf16x8 __attribute__((ext_vector_type(8)));
typedef float f32x4 __attribute__((ext_vector_type(4)));

// async global->LDS, 16 B per lane; LDS dest wave-uniform base (lane i -> +i*16)
__device__ __forceinline__ void async_copy16(const __bf16* g, __bf16* l) {
    __builtin_amdgcn_global_load_lds(
        (const __attribute__((address_space(1))) unsigned int*)g,
        (__attribute__((address_space(3))) unsigned int*)l,
        16, 0, 0);
}

// -------- fp32 -> swizzled bf16 tiles + sqc = (log2e)^2*||x||^2 --------
// Also zeroes out and the per-stripe done-counters (runs strictly before
// knn_mfma on the same stream). Tile = 16 rows; 16B chunk (ks*64 + q*16 + j)
// holds row j, k-range [(q+4ks)*8,+8) = MFMA fragment order.
__global__ __launch_bounds__(256)
void conv_swz_kernel(const float* __restrict__ x, __bf16* __restrict__ xswz,
                     float* __restrict__ sqc, float* __restrict__ out,
                     int* __restrict__ cnt, int n) {
    const int w = threadIdx.x >> 6, lane = threadIdx.x & 63;
    const int T = blockIdx.x * 4 + w;
    const int j = lane & 15, q = lane >> 4;
    if (threadIdx.x == 0) {
        cnt[blockIdx.x] = 0;                       // one stripe counter per block
        if (blockIdx.x == 0) *out = 0.0f;
    }
    const float* base = x + ((size_t)T * 16 + j) * D + q * 8;
    float4 v[8];
    #pragma unroll
    for (int ks = 0; ks < 4; ++ks) {
        v[2 * ks]     = *(const float4*)(base + ks * 32);
        v[2 * ks + 1] = *(const float4*)(base + ks * 32 + 4);
    }
    float s = 0.f;
    #pragma unroll
    for (int ks = 0; ks < 4; ++ks) {
        float4 u0 = v[2 * ks], u1 = v[2 * ks + 1];
        s += u0.x * u0.x + u0.y * u0.y + u0.z * u0.z + u0.w * u0.w;
        s += u1.x * u1.x + u1.y * u1.y + u1.z * u1.z + u1.w * u1.w;
        bf16x8 o;
        o[0] = (__bf16)u0.x; o[1] = (__bf16)u0.y; o[2] = (__bf16)u0.z; o[3] = (__bf16)u0.w;
        o[4] = (__bf16)u1.x; o[5] = (__bf16)u1.y; o[6] = (__bf16)u1.z; o[7] = (__bf16)u1.w;
        *(bf16x8*)(xswz + (size_t)T * 2048 + ((size_t)ks * 64 + lane) * 8) = o;
    }
    s += __shfl_xor(s, 16, 64);
    s += __shfl_xor(s, 32, 64);
    if (q == 0) sqc[T * 16 + j] = s * C_L2E2;
}

// ---------------- main fused MFMA kernel + last-arriver merge ----------------
// Block = 4 waves = 64 rows (wave w: A tile s*4+w). NSPLIT column splits.
// Batch = NT=4 tiles (16 KB), double-buffered, staged via global_load_lds.
// d2' = (log2e)^2*d2; exp(-d) = exp2(-sqrt(d2')). After partial writes, each
// block release-fences + bumps cnt[s]; the 8th arriver merges stripe s.
__global__ __launch_bounds__(256, 4)
void knn_mfma(const __bf16* __restrict__ xswz, const float* __restrict__ sqc,
              float* __restrict__ ptop, float* __restrict__ pdn,
              int* __restrict__ cnt, float* __restrict__ out, int n) {
    __shared__ __bf16 smem[2 * NT * 2048];   // 32 KB
    __shared__ int sdone;

    const int tid  = threadIdx.x;
    const int w    = tid >> 6;
    const int lane = tid & 63;
    const int quad = lane >> 4;
    const int l15  = lane & 15;
    const int s    = blockIdx.x >> 3;        // 64-row stripe (0..127)
    const int p    = blockIdx.x & (NSPLIT - 1);
    const int ta   = s * 4 + w;              // this wave's A tile
    const int tpsplit = (n / 16) / NSPLIT;   // 64 column tiles per block
    const int c0   = p * tpsplit;
    const int NITER = tpsplit / NT;          // 16

    bf16x8 a[4];
    {
        const __bf16* apt = xswz + (size_t)ta * 2048 + lane * 8;
        #pragma unroll
        for (int ks = 0; ks < 4; ++ks) a[ks] = *(const bf16x8*)(apt + ks * 512);
    }
    float sqa[4];
    #pragma unroll
    for (int r = 0; r < 4; ++r) sqa[r] = sqc[ta * 16 + quad * 4 + r];

    float h0[4], h1[4], dn[4];               // per-lane top-2 + denom partials
    #pragma unroll
    for (int r = 0; r < 4; ++r) { h0[r] = BIGF; h1[r] = BIGF; dn[r] = 0.f; }

    auto stage = [&](int buf, int i) {       // wave w stages tile cb+w (4 KB)
        int c = c0 + i * NT + w;
        const __bf16* src = xswz + (size_t)c * 2048 + lane * 8;
        __bf16* dst = &smem[buf * (NT * 2048) + w * 2048];
        #pragma unroll
        for (int ks = 0; ks < 4; ++ks)
            async_copy16(src + ks * 512, dst + ks * 512);
    };

    auto epi_fast = [&](const f32x4& acc, float sqb) {
        #pragma unroll
        for (int r = 0; r < 4; ++r) {
            float d2 = fmaxf(fmaf(-2.0f * C_L2E2, acc[r], sqa[r] + sqb), 0.0f);
            float dd = __builtin_amdgcn_sqrtf(d2);
            dn[r] += __builtin_amdgcn_exp2f(-dd);
            float t0 = fminf(h0[r], d2);
            float vm = fmaxf(h0[r], d2);
            h0[r] = t0;
            h1[r] = fminf(h1[r], vm);
        }
    };
    auto epi_diag = [&](const f32x4& acc, float sqb) {
        #pragma unroll
        for (int r = 0; r < 4; ++r) {
            float d2 = fmaxf(fmaf(-2.0f * C_L2E2, acc[r], sqa[r] + sqb), 0.0f);
            bool self = (quad * 4 + r == l15);
            float dd = __builtin_amdgcn_sqrtf(d2);
            float e  = __builtin_amdgcn_exp2f(-dd);
            dn[r] += self ? 0.0f : e;
            float v = self ? BIGF : d2;
            float t0 = fminf(h0[r], v);
            float vm = fmaxf(h0[r], v);
            h0[r] = t0;
            h1[r] = fminf(h1[r], vm);
        }
    };

    float sqb_cur[NT], sqb_nxt[NT];
    stage(0, 0);
    #pragma unroll
    for (int t = 0; t < NT; ++t) sqb_cur[t] = sqc[(c0 + t) * 16 + l15];

    for (int i = 0; i < NITER; ++i) {
        __syncthreads();                     // stage(i) complete; buf (i&1) readable
        if (i + 1 < NITER) stage((i + 1) & 1, i + 1);
        #pragma unroll
        for (int t = 0; t < NT; ++t)         // prefetch next sqb (tail: in-ws garbage, unused)
            sqb_nxt[t] = sqc[(c0 + (i + 1) * NT + t) * 16 + l15];

        const __bf16* bufp = &smem[(i & 1) * (NT * 2048)] + lane * 8;
        int cb = c0 + i * NT;
        #pragma unroll
        for (int tp = 0; tp < NT; tp += 2) { // two interleaved MFMA chains
            f32x4 acc1 = {0.f, 0.f, 0.f, 0.f};
            f32x4 acc2 = {0.f, 0.f, 0.f, 0.f};
            const __bf16* bp1 = bufp + tp * 2048;
            const __bf16* bp2 = bp1 + 2048;
            #pragma unroll
            for (int ks = 0; ks < 4; ++ks) {
                bf16x8 b1 = *(const bf16x8*)(bp1 + ks * 512);
                bf16x8 b2 = *(const bf16x8*)(bp2 + ks * 512);
                acc1 = __builtin_amdgcn_mfma_f32_16x16x32_bf16(a[ks], b1, acc1, 0, 0, 0);
                acc2 = __builtin_amdgcn_mfma_f32_16x16x32_bf16(a[ks], b2, acc2, 0, 0, 0);
            }
            bool dt1 = (cb + tp == ta);
            bool dt2 = (cb + tp + 1 == ta);
            if (dt1 || dt2) {                // wave-uniform, rare
                if (dt1) epi_diag(acc1, sqb_cur[tp]); else epi_fast(acc1, sqb_cur[tp]);
                if (dt2) epi_diag(acc2, sqb_cur[tp + 1]); else epi_fast(acc2, sqb_cur[tp + 1]);
            } else {
                epi_fast(acc1, sqb_cur[tp]);
                epi_fast(acc2, sqb_cur[tp + 1]);
            }
        }
        #pragma unroll
        for (int t = 0; t < NT; ++t) sqb_cur[t] = sqb_nxt[t];
    }

    // ---- per-wave merge (wave owns its 16 rows exclusively); write partials ----
    unsigned long long quadmask = 0xFFFFull << (quad * 16);
    #pragma unroll
    for (int r = 0; r < 4; ++r) {
        float d = dn[r];
        #pragma unroll
        for (int m = 8; m > 0; m >>= 1) d += __shfl_xor(d, m, 64);
        int row = ta * 16 + quad * 4 + r;
        float* pt = ptop + ((size_t)p * n + row) * KNN;
        for (int t = 0; t < KNN; ++t) {
            float lmin = h0[r];
            float gmin = lmin;
            #pragma unroll
            for (int m = 8; m > 0; m >>= 1) gmin = fminf(gmin, __shfl_xor(gmin, m, 64));
            if (l15 == 0) pt[t] = gmin;
            unsigned long long bal = __ballot(lmin == gmin) & quadmask;
            int owner = __ffsll(bal) - 1;
            if (lane == owner) { h0[r] = h1[r]; h1[r] = BIGF; }
        }
        if (l15 == 0) pdn[(size_t)p * n + row] = d;
    }

    // ---- last-arriver protocol: 8th block of this stripe merges its 64 rows ----
    __threadfence();                         // release: partials visible device-wide
    __syncthreads();                         // all waves' stores issued + fenced
    if (tid == 0) sdone = atomicAdd(&cnt[s], 1);
    __syncthreads();
    if (sdone != NSPLIT - 1) return;
    __threadfence();                         // acquire: other splits' partials visible

    if (tid < 64) {
        int row = s * 64 + tid;
        float dns[NSPLIT];
        #pragma unroll
        for (int sp = 0; sp < NSPLIT; ++sp) dns[sp] = pdn[(size_t)sp * n + row];

        float b8[KNN];
        {
            float4 p0 = *(const float4*)(ptop + (size_t)row * KNN);
            float4 p1 = *(const float4*)(ptop + (size_t)row * KNN + 4);
            b8[0] = p0.x; b8[1] = p0.y; b8[2] = p0.z; b8[3] = p0.w;
            b8[4] = p1.x; b8[5] = p1.y; b8[6] = p1.z; b8[7] = p1.w;
        }
        float dtot = dns[0];
        for (int sp = 1; sp < NSPLIT; ++sp) {
            dtot += dns[sp];
            const float* pt = ptop + ((size_t)sp * n + row) * KNN;
            float4 p0 = *(const float4*)pt;
            float4 p1 = *(const float4*)(pt + 4);
            float c[KNN] = {p0.x, p0.y, p0.z, p0.w, p1.x, p1.y, p1.z, p1.w};
            #pragma unroll
            for (int t = 0; t < KNN; ++t) {
                float v = c[t];
                #pragma unroll
                for (int q = 0; q < KNN; ++q) {
                    float lo = fminf(b8[q], v);
                    v = fmaxf(b8[q], v);
                    b8[q] = lo;
                }
            }
        }
        float sumd = 0.0f;
        #pragma unroll
        for (int t = 0; t < KNN; ++t) sumd += sqrtf(b8[t]);   // = d * log2e
        float loss = (sumd * (LN2 / KNN) + logf(dtot)) / (float)n;
        #pragma unroll
        for (int m = 32; m > 0; m >>= 1) loss += __shfl_xor(loss, m, 64);
        if (tid == 0) atomicAdd(out, loss);
    }
}

extern "C" void kernel_launch(void* const* d_in, const int* in_sizes, int n_in,
                              void* d_out, int out_size, void* d_ws, size_t ws_size,
                              hipStream_t stream) {
    const float* x = (const float*)d_in[0];
    int n = in_sizes[0] / D;                      // 8192
    char* ws = (char*)d_ws;
    __bf16* xswz = (__bf16*)ws;                   ws += (size_t)n * D * sizeof(__bf16);            // 2 MB
    float*  sqc  = (float*)ws;                    ws += (size_t)n * sizeof(float);                 // 32 KB
    float*  ptop = (float*)ws;                    ws += (size_t)NSPLIT * n * KNN * sizeof(float);  // 2 MB
    float*  pdn  = (float*)ws;                    ws += (size_t)NSPLIT * n * sizeof(float);        // 256 KB
    int*    cnt  = (int*)ws;                                                                       // 128 ints
    float*  out  = (float*)d_out;

    conv_swz_kernel<<<n / 64, 256, 0, stream>>>(x, xswz, sqc, out, cnt, n);
    knn_mfma<<<(n / 64) * NSPLIT, 256, 0, stream>>>(xswz, sqc, ptop, pdn, cnt, out, n);
}

// Round 12
// 112.617 us; speedup vs baseline: 2.1888x; 2.1888x over previous
//
#include <hip/hip_runtime.h>
#include <math.h>

#define D 128
#define KNN 8
#define NSPLIT 8
#define NT 4                       // column tiles staged per batch (one per wave)
#define BIGF 3.0e38f
#define C_L2E2 2.0813689810056077f // (log2 e)^2
#define LN2 0.6931471805599453f

typedef __bf16 bf16x8 __attribute__((ext_vector_type(8)));
typedef float f32x4 __attribute__((ext_vector_type(4)));

// async global->LDS, 16 B per lane; LDS dest wave-uniform base (lane i -> +i*16)
__device__ __forceinline__ void async_copy16(const __bf16* g, __bf16* l) {
    __builtin_amdgcn_global_load_lds(
        (const __attribute__((address_space(1))) unsigned int*)g,
        (__attribute__((address_space(3))) unsigned int*)l,
        16, 0, 0);
}

// Coherent-point (LLC) accessors: relaxed agent atomics compile to
// global_{store,load} sc0 sc1 — bypass the non-coherent per-XCD L2, NO
// buffer_wbl2/buffer_inv (the R11 disaster). Visibility across XCDs without
// any fence: stores complete at LLC before the arrival-counter RMW because
// __syncthreads() drains vmcnt first.
__device__ __forceinline__ void cstore(float* p, float v) {
    __hip_atomic_store(p, v, __ATOMIC_RELAXED, __HIP_MEMORY_SCOPE_AGENT);
}
__device__ __forceinline__ float cload(const float* p) {
    return __hip_atomic_load(p, __ATOMIC_RELAXED, __HIP_MEMORY_SCOPE_AGENT);
}

// -------- fp32 -> swizzled bf16 tiles + sqc = (log2e)^2*||x||^2 --------
// Also zeroes out + per-stripe done-counters (runs strictly before knn_mfma).
// Tile = 16 rows; 16B chunk (ks*64 + q*16 + j) holds row j, k-range
// [(q+4ks)*8,+8) = MFMA fragment order.
__global__ __launch_bounds__(256)
void conv_swz_kernel(const float* __restrict__ x, __bf16* __restrict__ xswz,
                     float* __restrict__ sqc, float* __restrict__ out,
                     int* __restrict__ cnt, int n) {
    const int w = threadIdx.x >> 6, lane = threadIdx.x & 63;
    const int T = blockIdx.x * 4 + w;
    const int j = lane & 15, q = lane >> 4;
    if (threadIdx.x == 0) {
        cnt[blockIdx.x] = 0;                       // one stripe counter per block
        if (blockIdx.x == 0) *out = 0.0f;
    }
    const float* base = x + ((size_t)T * 16 + j) * D + q * 8;
    float4 v[8];
    #pragma unroll
    for (int ks = 0; ks < 4; ++ks) {
        v[2 * ks]     = *(const float4*)(base + ks * 32);
        v[2 * ks + 1] = *(const float4*)(base + ks * 32 + 4);
    }
    float s = 0.f;
    #pragma unroll
    for (int ks = 0; ks < 4; ++ks) {
        float4 u0 = v[2 * ks], u1 = v[2 * ks + 1];
        s += u0.x * u0.x + u0.y * u0.y + u0.z * u0.z + u0.w * u0.w;
        s += u1.x * u1.x + u1.y * u1.y + u1.z * u1.z + u1.w * u1.w;
        bf16x8 o;
        o[0] = (__bf16)u0.x; o[1] = (__bf16)u0.y; o[2] = (__bf16)u0.z; o[3] = (__bf16)u0.w;
        o[4] = (__bf16)u1.x; o[5] = (__bf16)u1.y; o[6] = (__bf16)u1.z; o[7] = (__bf16)u1.w;
        *(bf16x8*)(xswz + (size_t)T * 2048 + ((size_t)ks * 64 + lane) * 8) = o;
    }
    s += __shfl_xor(s, 16, 64);
    s += __shfl_xor(s, 32, 64);
    if (q == 0) sqc[T * 16 + j] = s * C_L2E2;
}

// ---------------- main fused MFMA kernel + fence-free last-arriver merge ----
__global__ __launch_bounds__(256, 4)
void knn_mfma(const __bf16* __restrict__ xswz, const float* __restrict__ sqc,
              float* __restrict__ ptop, float* __restrict__ pdn,
              int* __restrict__ cnt, float* __restrict__ out, int n) {
    __shared__ __bf16 smem[2 * NT * 2048];   // 32 KB
    __shared__ int sdone;

    const int tid  = threadIdx.x;
    const int w    = tid >> 6;
    const int lane = tid & 63;
    const int quad = lane >> 4;
    const int l15  = lane & 15;
    const int s    = blockIdx.x >> 3;        // 64-row stripe (0..127)
    const int p    = blockIdx.x & (NSPLIT - 1);
    const int ta   = s * 4 + w;              // this wave's A tile
    const int tpsplit = (n / 16) / NSPLIT;   // 64 column tiles per block
    const int c0   = p * tpsplit;
    const int NITER = tpsplit / NT;          // 16

    bf16x8 a[4];
    {
        const __bf16* apt = xswz + (size_t)ta * 2048 + lane * 8;
        #pragma unroll
        for (int ks = 0; ks < 4; ++ks) a[ks] = *(const bf16x8*)(apt + ks * 512);
    }
    float sqa[4];
    #pragma unroll
    for (int r = 0; r < 4; ++r) sqa[r] = sqc[ta * 16 + quad * 4 + r];

    float h0[4], h1[4], dn[4];               // per-lane top-2 + denom partials
    #pragma unroll
    for (int r = 0; r < 4; ++r) { h0[r] = BIGF; h1[r] = BIGF; dn[r] = 0.f; }

    auto stage = [&](int buf, int i) {       // wave w stages tile cb+w (4 KB)
        int c = c0 + i * NT + w;
        const __bf16* src = xswz + (size_t)c * 2048 + lane * 8;
        __bf16* dst = &smem[buf * (NT * 2048) + w * 2048];
        #pragma unroll
        for (int ks = 0; ks < 4; ++ks)
            async_copy16(src + ks * 512, dst + ks * 512);
    };

    auto epi_fast = [&](const f32x4& acc, float sqb) {
        #pragma unroll
        for (int r = 0; r < 4; ++r) {
            float d2 = fmaxf(fmaf(-2.0f * C_L2E2, acc[r], sqa[r] + sqb), 0.0f);
            float dd = __builtin_amdgcn_sqrtf(d2);
            dn[r] += __builtin_amdgcn_exp2f(-dd);
            float t0 = fminf(h0[r], d2);
            float vm = fmaxf(h0[r], d2);
            h0[r] = t0;
            h1[r] = fminf(h1[r], vm);
        }
    };
    auto epi_diag = [&](const f32x4& acc, float sqb) {
        #pragma unroll
        for (int r = 0; r < 4; ++r) {
            float d2 = fmaxf(fmaf(-2.0f * C_L2E2, acc[r], sqa[r] + sqb), 0.0f);
            bool self = (quad * 4 + r == l15);
            float dd = __builtin_amdgcn_sqrtf(d2);
            float e  = __builtin_amdgcn_exp2f(-dd);
            dn[r] += self ? 0.0f : e;
            float v = self ? BIGF : d2;
            float t0 = fminf(h0[r], v);
            float vm = fmaxf(h0[r], v);
            h0[r] = t0;
            h1[r] = fminf(h1[r], vm);
        }
    };

    float sqb_cur[NT], sqb_nxt[NT];
    stage(0, 0);
    #pragma unroll
    for (int t = 0; t < NT; ++t) sqb_cur[t] = sqc[(c0 + t) * 16 + l15];

    for (int i = 0; i < NITER; ++i) {
        __syncthreads();                     // stage(i) complete; buf (i&1) readable
        if (i + 1 < NITER) stage((i + 1) & 1, i + 1);
        #pragma unroll
        for (int t = 0; t < NT; ++t)         // prefetch next sqb (tail: in-ws garbage, unused)
            sqb_nxt[t] = sqc[(c0 + (i + 1) * NT + t) * 16 + l15];

        const __bf16* bufp = &smem[(i & 1) * (NT * 2048)] + lane * 8;
        int cb = c0 + i * NT;
        #pragma unroll
        for (int tp = 0; tp < NT; tp += 2) { // two interleaved MFMA chains
            f32x4 acc1 = {0.f, 0.f, 0.f, 0.f};
            f32x4 acc2 = {0.f, 0.f, 0.f, 0.f};
            const __bf16* bp1 = bufp + tp * 2048;
            const __bf16* bp2 = bp1 + 2048;
            #pragma unroll
            for (int ks = 0; ks < 4; ++ks) {
                bf16x8 b1 = *(const bf16x8*)(bp1 + ks * 512);
                bf16x8 b2 = *(const bf16x8*)(bp2 + ks * 512);
                acc1 = __builtin_amdgcn_mfma_f32_16x16x32_bf16(a[ks], b1, acc1, 0, 0, 0);
                acc2 = __builtin_amdgcn_mfma_f32_16x16x32_bf16(a[ks], b2, acc2, 0, 0, 0);
            }
            bool dt1 = (cb + tp == ta);
            bool dt2 = (cb + tp + 1 == ta);
            if (dt1 || dt2) {                // wave-uniform, rare
                if (dt1) epi_diag(acc1, sqb_cur[tp]); else epi_fast(acc1, sqb_cur[tp]);
                if (dt2) epi_diag(acc2, sqb_cur[tp + 1]); else epi_fast(acc2, sqb_cur[tp + 1]);
            } else {
                epi_fast(acc1, sqb_cur[tp]);
                epi_fast(acc2, sqb_cur[tp + 1]);
            }
        }
        #pragma unroll
        for (int t = 0; t < NT; ++t) sqb_cur[t] = sqb_nxt[t];
    }

    // ---- per-wave merge; write partials straight to the coherent point ----
    unsigned long long quadmask = 0xFFFFull << (quad * 16);
    #pragma unroll
    for (int r = 0; r < 4; ++r) {
        float d = dn[r];
        #pragma unroll
        for (int m = 8; m > 0; m >>= 1) d += __shfl_xor(d, m, 64);
        int row = ta * 16 + quad * 4 + r;
        float* pt = ptop + ((size_t)p * n + row) * KNN;
        for (int t = 0; t < KNN; ++t) {
            float lmin = h0[r];
            float gmin = lmin;
            #pragma unroll
            for (int m = 8; m > 0; m >>= 1) gmin = fminf(gmin, __shfl_xor(gmin, m, 64));
            if (l15 == 0) cstore(&pt[t], gmin);
            unsigned long long bal = __ballot(lmin == gmin) & quadmask;
            int owner = __ffsll(bal) - 1;
            if (lane == owner) { h0[r] = h1[r]; h1[r] = BIGF; }
        }
        if (l15 == 0) cstore(&pdn[(size_t)p * n + row], d);
    }

    // ---- fence-free last-arriver: __syncthreads drains all waves' vmcnt,
    //      so every cstore above has completed at the LLC before the RMW ----
    __syncthreads();
    if (tid == 0)
        sdone = __hip_atomic_fetch_add(&cnt[s], 1, __ATOMIC_RELAXED,
                                       __HIP_MEMORY_SCOPE_AGENT);
    __syncthreads();
    if (sdone != NSPLIT - 1) return;

    if (tid < 64) {                          // winner merges its stripe's 64 rows
        int row = s * 64 + tid;
        float dtot = 0.0f;
        float b8[KNN];
        #pragma unroll
        for (int t = 0; t < KNN; ++t) b8[t] = BIGF;
        for (int sp = 0; sp < NSPLIT; ++sp) {
            dtot += cload(&pdn[(size_t)sp * n + row]);
            const float* pt = ptop + ((size_t)sp * n + row) * KNN;
            #pragma unroll
            for (int t = 0; t < KNN; ++t) {
                float v = cload(&pt[t]);
                #pragma unroll
                for (int q = 0; q < KNN; ++q) {
                    float lo = fminf(b8[q], v);
                    v = fmaxf(b8[q], v);
                    b8[q] = lo;
                }
            }
        }
        float sumd = 0.0f;
        #pragma unroll
        for (int t = 0; t < KNN; ++t) sumd += sqrtf(b8[t]);   // = d * log2e
        float loss = (sumd * (LN2 / KNN) + logf(dtot)) / (float)n;
        #pragma unroll
        for (int m = 32; m > 0; m >>= 1) loss += __shfl_xor(loss, m, 64);
        if (tid == 0) atomicAdd(out, loss);
    }
}

extern "C" void kernel_launch(void* const* d_in, const int* in_sizes, int n_in,
                              void* d_out, int out_size, void* d_ws, size_t ws_size,
                              hipStream_t stream) {
    const float* x = (const float*)d_in[0];
    int n = in_sizes[0] / D;                      // 8192
    char* ws = (char*)d_ws;
    __bf16* xswz = (__bf16*)ws;                   ws += (size_t)n * D * sizeof(__bf16);            // 2 MB
    float*  sqc  = (float*)ws;                    ws += (size_t)n * sizeof(float);                 // 32 KB
    float*  ptop = (float*)ws;                    ws += (size_t)NSPLIT * n * KNN * sizeof(float);  // 2 MB
    float*  pdn  = (float*)ws;                    ws += (size_t)NSPLIT * n * sizeof(float);        // 256 KB
    int*    cnt  = (int*)ws;                                                                       // 128 ints
    float*  out  = (float*)d_out;

    conv_swz_kernel<<<n / 64, 256, 0, stream>>>(x, xswz, sqc, out, cnt, n);
    knn_mfma<<<(n / 64) * NSPLIT, 256, 0, stream>>>(xswz, sqc, ptop, pdn, cnt, out, n);
}